// Round 12
// baseline (535.624 us; speedup 1.0000x reference)
//
#include <hip/hip_runtime.h>
#include <stdint.h>

#define N_NODES 50000
#define N_EDGES 600000
#define DIM 128
#define NGRAPH 128
#define POOL_ROWS 100

typedef __bf16 bf16x8 __attribute__((ext_vector_type(8)));
typedef float f32x4 __attribute__((ext_vector_type(4)));
typedef unsigned short u16;
typedef unsigned int u32;
typedef long long i64;

__device__ __forceinline__ float bf2f(u16 a) {
  union { u32 u; float f; } x; x.u = ((u32)a) << 16; return x.f;
}
__device__ __forceinline__ u16 f2bf(float f) {
  union { float f; u32 u; } x; x.f = f;
  u32 u = x.u;
  u32 r = (u + 0x7FFFu + ((u >> 16) & 1u)) >> 16;
  return (u16)r;
}
__device__ __forceinline__ void unpack8(uint4 v, float* f) {
  f[0] = bf2f((u16)(v.x & 0xFFFF)); f[1] = bf2f((u16)(v.x >> 16));
  f[2] = bf2f((u16)(v.y & 0xFFFF)); f[3] = bf2f((u16)(v.y >> 16));
  f[4] = bf2f((u16)(v.z & 0xFFFF)); f[5] = bf2f((u16)(v.z >> 16));
  f[6] = bf2f((u16)(v.w & 0xFFFF)); f[7] = bf2f((u16)(v.w >> 16));
}

// ---------------- sentinel (fp32 out) ----------------
__global__ void sentinel_fill(float* __restrict__ out, int n, float code) {
  int i = blockIdx.x * 256 + threadIdx.x;
  if (i < n) out[i] = code;
}

// ---------------- dtype detection (parallel) ----------------
__global__ void detect_dtypes(const u16* __restrict__ xu, const int* __restrict__ ei,
                              const int* __restrict__ bat, int* __restrict__ flags) {
  int gid = blockIdx.x * 256 + threadIdx.x;    // 32768 threads
  int c0 = 0;
  for (int i = gid; i < 200000; i += 32768) c0 += ((xu[i] & 0x7F80) == 0x7F80) ? 1 : 0;
  if (c0) atomicAdd(&flags[0], c0);
  if (gid < 2048 && ei[1 + gid * 586] != 0) atomicAdd(&flags[1], 1);
  if (gid < 2000 && bat[1 + gid * 24] != 0) atomicAdd(&flags[2], 1);
}

__device__ __forceinline__ void load_edge(const int* __restrict__ ei, bool is64, int e,
                                          int& s, int& d) {
  if (is64) {
    s = (int)((const i64*)ei)[e];
    d = (int)((const i64*)ei)[(size_t)N_EDGES + e];
  } else {
    s = ei[e];
    d = ei[N_EDGES + e];
  }
  s = min(max(s, 0), N_NODES - 1);
  d = min(max(d, 0), N_NODES - 1);
}

// ---------------- x → bf16 Hb (once) ----------------
__global__ void convert_x(const void* __restrict__ x, const int* __restrict__ flags,
                          u16* __restrict__ Hb) {
  int i = blockIdx.x * 256 + threadIdx.x;     // 8-elem chunk id
  const int total = N_NODES * DIM / 8;        // 800000
  if (i >= total) return;
  union { u16 h[8]; uint4 q; } pk;
  if (flags[0] > 0) {
    const float4* xf = (const float4*)x;
    float4 a = xf[(size_t)i * 2], b = xf[(size_t)i * 2 + 1];
    pk.h[0] = f2bf(a.x); pk.h[1] = f2bf(a.y); pk.h[2] = f2bf(a.z); pk.h[3] = f2bf(a.w);
    pk.h[4] = f2bf(b.x); pk.h[5] = f2bf(b.y); pk.h[6] = f2bf(b.z); pk.h[7] = f2bf(b.w);
  } else {
    pk.q = ((const uint4*)x)[i];
  }
  ((uint4*)Hb)[i] = pk.q;
}

// ---------------- weight prep: WT[(l*4+m)][j*128+k] = bf16(W[k][j]) ----------
__global__ void prep_wt(const void* __restrict__ Wq, const void* __restrict__ Wk,
                        const void* __restrict__ Wv, const void* __restrict__ Ws,
                        u16* __restrict__ WT, const int* __restrict__ flags) {
  int b = blockIdx.x;            // 0..11 = l*4+m
  int l = b >> 2, m = b & 3;
  bool f32 = flags[0] > 0;
  const void* W = (m == 0 ? Wq : m == 1 ? Wk : m == 2 ? Wv : Ws);
  size_t base = (size_t)l * DIM * DIM;
  u16* out = WT + (size_t)b * DIM * DIM;
  for (int idx = threadIdx.x; idx < DIM * DIM; idx += 256) {
    int j = idx >> 7, k = idx & 127;
    float v;
    if (f32) v = ((const float*)W)[base + (size_t)k * DIM + j];
    else     v = bf2f(((const u16*)W)[base + (size_t)k * DIM + j]);
    out[idx] = f2bf(v);
  }
}

__global__ void canon_bias(const void* __restrict__ bq, const void* __restrict__ bk,
                           const void* __restrict__ bv, const void* __restrict__ bs,
                           float* __restrict__ biasc, const int* __restrict__ flags) {
  bool f32 = flags[0] > 0;
  for (int idx = threadIdx.x; idx < 12 * DIM; idx += 256) {
    int b = idx >> 7, d = idx & 127;
    int l = b >> 2, m = b & 3;
    const void* p = (m == 0 ? bq : m == 1 ? bk : m == 2 ? bv : bs);
    float v;
    if (f32) v = ((const float*)p)[l * DIM + d];
    else     v = bf2f(((const u16*)p)[l * DIM + d]);
    biasc[idx] = v;
  }
}

// ---------------- fused q/k/v/skip GEMM: bf16 H, one matrix per block ----------
__global__ __launch_bounds__(256) void gemm_qkvs(
    const u16* __restrict__ Hb, const u16* __restrict__ WT,
    const float* __restrict__ biasc,
    u16* __restrict__ Q, u16* __restrict__ K, u16* __restrict__ V, u16* __restrict__ S) {
  __shared__ u16 As[64][136];    // 17.4 KB
  __shared__ u16 Bs[128][136];   // 34.8 KB
  int tid = threadIdx.x;
  int r0 = blockIdx.x * 64;
  int mat = blockIdx.y;
  const u16* Wt = WT + (size_t)mat * DIM * DIM;

  for (int it = 0; it < 4; ++it) {
    int i16 = it * 256 + tid;
    int row = i16 >> 4, seg = i16 & 15;
    uint4 val = make_uint4(0, 0, 0, 0);
    if (r0 + row < N_NODES) val = ((const uint4*)Hb)[(size_t)(r0 + row) * 16 + seg];
    *((uint4*)&As[row][seg * 8]) = val;
  }
  for (int it = 0; it < 8; ++it) {
    int i16 = it * 256 + tid;
    int j = i16 >> 4, seg = i16 & 15;
    uint4 val = ((const uint4*)Wt)[j * 16 + seg];
    *((uint4*)&Bs[j][seg * 8]) = val;
  }
  __syncthreads();

  int lane = tid & 63;
  int w = tid >> 6;
  int wm = w & 1, wn = w >> 1;
  int lrow = lane & 15;
  int kq = (lane >> 4) * 8;
  f32x4 acc[2][4] = {};
#pragma unroll
  for (int kt = 0; kt < 4; ++kt) {
    int k0 = kt * 32 + kq;
    bf16x8 a0 = *((const bf16x8*)&As[wm * 32 + lrow][k0]);
    bf16x8 a1 = *((const bf16x8*)&As[wm * 32 + 16 + lrow][k0]);
#pragma unroll
    for (int ni = 0; ni < 4; ++ni) {
      bf16x8 b = *((const bf16x8*)&Bs[wn * 64 + ni * 16 + lrow][k0]);
      acc[0][ni] = __builtin_amdgcn_mfma_f32_16x16x32_bf16(a0, b, acc[0][ni], 0, 0, 0);
      acc[1][ni] = __builtin_amdgcn_mfma_f32_16x16x32_bf16(a1, b, acc[1][ni], 0, 0, 0);
    }
  }

  const float* bias = biasc + mat * DIM;
  u16* Out = (mat == 0 ? Q : mat == 1 ? K : mat == 2 ? V : S);
#pragma unroll
  for (int mi = 0; mi < 2; ++mi)
#pragma unroll
    for (int ni = 0; ni < 4; ++ni) {
      int colg = wn * 64 + ni * 16 + lrow;
      float bvf = bias[colg];
#pragma unroll
      for (int r = 0; r < 4; ++r) {
        int rowg = r0 + wm * 32 + mi * 16 + (lane >> 4) * 4 + r;
        if (rowg < N_NODES) {
          float o = acc[mi][ni][r] + bvf;
          if (!(o - o == 0.0f)) o = 7000.0f;
          Out[(size_t)rowg * DIM + colg] = f2bf(o);
        }
      }
    }
}

// ---------------- CSR build ----------------
__global__ void count_deg(const int* __restrict__ ei, const int* __restrict__ flags,
                          int* __restrict__ deg) {
  int e = blockIdx.x * 256 + threadIdx.x;
  if (e < N_EDGES) {
    int s, d;
    load_edge(ei, flags[1] == 0, e, s, d);
    atomicAdd(&deg[d], 1);
  }
}

__global__ void scan_blk(const int* __restrict__ deg, int* __restrict__ row_ptr,
                         int* __restrict__ blksum) {
  __shared__ int buf[1024];
  int tid = threadIdx.x;
  int idx = blockIdx.x * 1024 + tid;
  int v = (idx < N_NODES) ? deg[idx] : 0;
  buf[tid] = v;
  __syncthreads();
  for (int off = 1; off < 1024; off <<= 1) {
    int t = (tid >= off) ? buf[tid - off] : 0;
    __syncthreads();
    buf[tid] += t;
    __syncthreads();
  }
  if (idx < N_NODES) row_ptr[idx + 1] = buf[tid];
  if (tid == 1023) blksum[blockIdx.x] = buf[1023];
}

__global__ void scan_sums(int* __restrict__ blksum, int nblk) {
  if (threadIdx.x == 0) {
    int run = 0;
    for (int b = 0; b < nblk; ++b) { int t = blksum[b]; blksum[b] = run; run += t; }
  }
}

__global__ void scan_add(int* __restrict__ row_ptr, const int* __restrict__ blksum) {
  int idx = blockIdx.x * 1024 + threadIdx.x;
  if (idx < N_NODES) row_ptr[idx + 1] += blksum[blockIdx.x];
  if (idx == 0) row_ptr[0] = 0;
}

__global__ void fill_csr(const int* __restrict__ ei, const int* __restrict__ flags,
                         const int* __restrict__ row_ptr, int* __restrict__ deg,
                         int* __restrict__ csr_src) {
  int e = blockIdx.x * 256 + threadIdx.x;
  if (e < N_EDGES) {
    int s, d;
    load_edge(ei, flags[1] == 0, e, s, d);
    int c = atomicSub(&deg[d], 1);
    int pos = row_ptr[d] + c - 1;
    if (pos >= 0 && pos < N_EDGES) csr_src[pos] = s;
  }
}

// ---------------- attention: 1 wave/node, 8 groups x 8 lanes ----------------
// group g handles edges start+g, start+g+8, ... ; lane sl covers dims sl*16..sl*16+15
// (2 x uint4 per row). 8 edges & 32 16B-loads in flight per wave-iteration.
__global__ __launch_bounds__(256) void attn_agg(
    const u16* __restrict__ Q, const u16* __restrict__ Kb,
    const u16* __restrict__ V, const u16* __restrict__ S,
    const int* __restrict__ row_ptr, const int* __restrict__ csr_src,
    void* __restrict__ Hout, int apply_relu, int out_f32) {
  int wid = threadIdx.x >> 6;
  int lane = threadIdx.x & 63;
  int n = blockIdx.x * 4 + wid;
  if (n >= N_NODES) return;
  int g = lane >> 3;            // 0..7
  int sl = lane & 7;            // 0..7
  int d0 = sl * 16;
  uint4 qv0 = *((const uint4*)&Q[(size_t)n * DIM + d0]);
  uint4 qv1 = *((const uint4*)&Q[(size_t)n * DIM + d0 + 8]);
  float q[16]; unpack8(qv0, q); unpack8(qv1, q + 8);
  int start = row_ptr[n], end = row_ptr[n + 1];
  start = min(max(start, 0), N_EDGES);
  end = min(max(end, start), N_EDGES);
  const float scale = 0.0883883476483184f;  // 1/sqrt(128)
  float m = -INFINITY, lsum = 0.f;
  float acc[16] = {};
  for (int e = start + g; e < end; e += 8) {
    int srcn = csr_src[e];
    srcn = min(max(srcn, 0), N_NODES - 1);
    const u16* krow = &Kb[(size_t)srcn * DIM + d0];
    const u16* vrow = &V[(size_t)srcn * DIM + d0];
    uint4 kv0 = *((const uint4*)krow);
    uint4 kv1 = *((const uint4*)(krow + 8));
    uint4 vv0 = *((const uint4*)vrow);
    uint4 vv1 = *((const uint4*)(vrow + 8));
    float kf[16], vf[16];
    unpack8(kv0, kf); unpack8(kv1, kf + 8);
    unpack8(vv0, vf); unpack8(vv1, vf + 8);
    float p = 0.f;
#pragma unroll
    for (int j = 0; j < 16; ++j) p += q[j] * kf[j];
    p += __shfl_xor(p, 1, 64);
    p += __shfl_xor(p, 2, 64);
    p += __shfl_xor(p, 4, 64);
    float s = p * scale;
    float mn = fmaxf(m, s);
    float wold = __expf(m - mn);
    float wnew = __expf(s - mn);
    lsum = lsum * wold + wnew;
#pragma unroll
    for (int j = 0; j < 16; ++j) acc[j] = acc[j] * wold + wnew * vf[j];
    m = mn;
  }
  // merge 8 group states (same dims in lanes sl+8k)
#pragma unroll
  for (int off = 8; off <= 32; off <<= 1) {
    float mo = __shfl_xor(m, off, 64);
    float lo = __shfl_xor(lsum, off, 64);
    float ao[16];
#pragma unroll
    for (int j = 0; j < 16; ++j) ao[j] = __shfl_xor(acc[j], off, 64);
    float mn = fmaxf(m, mo);
    float wa = (m  > -INFINITY) ? __expf(m  - mn) : 0.f;
    float wb = (mo > -INFINITY) ? __expf(mo - mn) : 0.f;
    lsum = lsum * wa + lo * wb;
#pragma unroll
    for (int j = 0; j < 16; ++j) acc[j] = acc[j] * wa + ao[j] * wb;
    m = mn;
  }
  float inv = (lsum > 0.f) ? (1.0f / lsum) : 0.f;
  uint4 sv0 = *((const uint4*)&S[(size_t)n * DIM + d0]);
  uint4 sv1 = *((const uint4*)&S[(size_t)n * DIM + d0 + 8]);
  float sf[16]; unpack8(sv0, sf); unpack8(sv1, sf + 8);
  float o[16];
#pragma unroll
  for (int j = 0; j < 16; ++j) {
    float v = acc[j] * inv + sf[j];
    if (apply_relu) v = (v >= 0.f) ? v : 0.01f * v;
    if (!(v - v == 0.0f)) v = 9000.0f;
    o[j] = v;
  }
  if (g == 0) {
    if (out_f32) {
      float* H = (float*)Hout;
#pragma unroll
      for (int c = 0; c < 4; ++c)
        *((float4*)&H[(size_t)n * DIM + d0 + c * 4]) =
            make_float4(o[c * 4], o[c * 4 + 1], o[c * 4 + 2], o[c * 4 + 3]);
    } else {
      union { u16 h[8]; uint4 q; } pk0, pk1;
#pragma unroll
      for (int j = 0; j < 8; ++j) { pk0.h[j] = f2bf(o[j]); pk1.h[j] = f2bf(o[j + 8]); }
      u16* H = (u16*)Hout;
      *((uint4*)&H[(size_t)n * DIM + d0]) = pk0.q;
      *((uint4*)&H[(size_t)n * DIM + d0 + 8]) = pk1.q;
    }
  }
}

// ---------------- parallel mean pool ----------------
__device__ __forceinline__ int bat_at(const int* bat, int i, bool is64) {
  return is64 ? (int)((const i64*)bat)[i] : bat[i];
}

__global__ __launch_bounds__(128) void pool_partial(
    const float* __restrict__ node_emb, const int* __restrict__ bat,
    const int* __restrict__ flags, float* __restrict__ gsum, float* __restrict__ gcnt) {
  int t = threadIdx.x;
  int r0 = blockIdx.x * POOL_ROWS;
  int rend = min(r0 + POOL_ROWS, N_NODES);
  if (r0 >= rend) return;
  bool is64 = (flags[2] == 0);
  int cur = min(max(bat_at(bat, r0, is64), 0), NGRAPH - 1);
  float acc = 0.f;
  int cnt = 0;
  for (int i = r0; i < rend; ++i) {
    int b = min(max(bat_at(bat, i, is64), 0), NGRAPH - 1);
    if (b != cur) {
      atomicAdd(&gsum[cur * DIM + t], acc);
      if (t == 0) atomicAdd(&gcnt[cur], (float)cnt);
      acc = 0.f; cnt = 0; cur = b;
    }
    acc += node_emb[(size_t)i * DIM + t];
    ++cnt;
  }
  atomicAdd(&gsum[cur * DIM + t], acc);
  if (t == 0) atomicAdd(&gcnt[cur], (float)cnt);
}

__global__ void pool_final(const float* __restrict__ gsum, const float* __restrict__ gcnt,
                           float* __restrict__ graph_emb) {
  int i = blockIdx.x * 256 + threadIdx.x;
  if (i < NGRAPH * DIM) {
    int b = i >> 7;
    float g = gsum[i] / fmaxf(gcnt[b], 1.0f);
    if (!(g - g == 0.0f)) g = 5555.0f;
    graph_emb[i] = g;
  }
}

extern "C" void kernel_launch(void* const* d_in, const int* in_sizes, int n_in,
                              void* d_out, int out_size, void* d_ws, size_t ws_size,
                              hipStream_t stream) {
  static const int EXP_SIZES[11] = {6400000, 1200000, 50000,
                                    49152, 384, 49152, 384, 49152, 384, 49152, 384};
  {
    float code = 0.0f;
    if (n_in != 11) code = 40000.0f;
    else if (out_size != 6416384) code = 42000.0f;
    else {
      for (int i = 0; i < 11; ++i)
        if (in_sizes[i] != EXP_SIZES[i]) { code = 44000.0f + 400.0f * i; break; }
    }
    if (code != 0.0f) {
      sentinel_fill<<<(out_size + 255) / 256, 256, 0, stream>>>((float*)d_out, out_size, code);
      return;
    }
  }

  const u16* x   = (const u16*)d_in[0];
  const int* ei  = (const int*)d_in[1];
  const int* bat = (const int*)d_in[2];

  const size_t NEEDED = 54465936;
  if (ws_size < NEEDED) {
    float code = 1000.0f + (float)(ws_size >> 20);
    sentinel_fill<<<(out_size + 255) / 256, 256, 0, stream>>>((float*)d_out, out_size, code);
    return;
  }

  char* w = (char*)d_ws;
  int*   flags   = (int*)w;   w += 256;
  int*   blksum  = (int*)w;   w += 256;
  float* gsum    = (float*)w; w += (size_t)NGRAPH * DIM * 4;
  float* gcnt    = (float*)w; w += (size_t)NGRAPH * 4;
  int*   deg     = (int*)w;   w += (size_t)N_NODES * 4;
  int*   row_ptr = (int*)w;   w += (size_t)(N_NODES + 4) * 4;
  int*   csr_src = (int*)w;   w += (size_t)N_EDGES * 4;
  u16*   WT      = (u16*)w;   w += (size_t)12 * DIM * DIM * 2;
  float* biasc   = (float*)w; w += (size_t)12 * DIM * 4;
  const size_t ND2 = (size_t)N_NODES * DIM * 2;
  u16* Qb = (u16*)w; w += ND2;
  u16* Kb = (u16*)w; w += ND2;
  u16* Vb = (u16*)w; w += ND2;
  u16* Sb = (u16*)w; w += ND2;

  hipMemsetAsync(flags, 0, 512 + 65536 + 512 + (size_t)N_NODES * 4, stream);

  detect_dtypes<<<128, 256, 0, stream>>>(x, ei, bat, flags);
  prep_wt<<<12, 256, 0, stream>>>(d_in[3], d_in[5], d_in[7], d_in[9], WT, flags);
  canon_bias<<<1, 256, 0, stream>>>(d_in[4], d_in[6], d_in[8], d_in[10], biasc, flags);

  u16* Hb = (u16*)d_out;   // bf16 h aliases d_out node region (fp32) — safe, see R11
  convert_x<<<(N_NODES * DIM / 8 + 255) / 256, 256, 0, stream>>>(x, flags, Hb);

  int eblocks = (N_EDGES + 255) / 256;
  int nblk = (N_NODES + 1023) / 1024;   // 49
  count_deg<<<eblocks, 256, 0, stream>>>(ei, flags, deg);
  scan_blk<<<nblk, 1024, 0, stream>>>(deg, row_ptr, blksum);
  scan_sums<<<1, 64, 0, stream>>>(blksum, nblk);
  scan_add<<<nblk, 1024, 0, stream>>>(row_ptr, blksum);
  fill_csr<<<eblocks, 256, 0, stream>>>(ei, flags, row_ptr, deg, csr_src);

  float* node_out = (float*)d_out;
  for (int l = 0; l < 3; ++l) {
    gemm_qkvs<<<dim3((N_NODES + 63) / 64, 4), 256, 0, stream>>>(
        Hb, WT + (size_t)l * 4 * DIM * DIM, biasc + (size_t)l * 4 * DIM,
        Qb, Kb, Vb, Sb);
    if (l < 2)
      attn_agg<<<(N_NODES + 3) / 4, 256, 0, stream>>>(Qb, Kb, Vb, Sb, row_ptr, csr_src,
                                                      (void*)Hb, 1, 0);
    else
      attn_agg<<<(N_NODES + 3) / 4, 256, 0, stream>>>(Qb, Kb, Vb, Sb, row_ptr, csr_src,
                                                      (void*)node_out, 0, 1);
  }
  int pblocks = (N_NODES + POOL_ROWS - 1) / POOL_ROWS;   // 500
  pool_partial<<<pblocks, 128, 0, stream>>>(node_out, bat, flags, gsum, gcnt);
  pool_final<<<(NGRAPH * DIM + 255) / 256, 256, 0, stream>>>(gsum, gcnt,
                                                             node_out + (size_t)N_NODES * DIM);
}

// Round 13
// 521.011 us; speedup vs baseline: 1.0280x; 1.0280x over previous
//
#include <hip/hip_runtime.h>
#include <stdint.h>

#define N_NODES 50000
#define N_EDGES 600000
#define DIM 128
#define NGRAPH 128
#define POOL_ROWS 100

typedef __bf16 bf16x8 __attribute__((ext_vector_type(8)));
typedef float f32x4 __attribute__((ext_vector_type(4)));
typedef unsigned short u16;
typedef unsigned int u32;
typedef long long i64;

__device__ __forceinline__ float bf2f(u16 a) {
  union { u32 u; float f; } x; x.u = ((u32)a) << 16; return x.f;
}
__device__ __forceinline__ u16 f2bf(float f) {
  union { float f; u32 u; } x; x.f = f;
  u32 u = x.u;
  u32 r = (u + 0x7FFFu + ((u >> 16) & 1u)) >> 16;
  return (u16)r;
}
__device__ __forceinline__ void unpack8(uint4 v, float* f) {
  f[0] = bf2f((u16)(v.x & 0xFFFF)); f[1] = bf2f((u16)(v.x >> 16));
  f[2] = bf2f((u16)(v.y & 0xFFFF)); f[3] = bf2f((u16)(v.y >> 16));
  f[4] = bf2f((u16)(v.z & 0xFFFF)); f[5] = bf2f((u16)(v.z >> 16));
  f[6] = bf2f((u16)(v.w & 0xFFFF)); f[7] = bf2f((u16)(v.w >> 16));
}

// ---------------- sentinel (fp32 out) ----------------
__global__ void sentinel_fill(float* __restrict__ out, int n, float code) {
  int i = blockIdx.x * 256 + threadIdx.x;
  if (i < n) out[i] = code;
}

// ---------------- dtype detection (parallel) ----------------
__global__ void detect_dtypes(const u16* __restrict__ xu, const int* __restrict__ ei,
                              const int* __restrict__ bat, int* __restrict__ flags) {
  int gid = blockIdx.x * 256 + threadIdx.x;    // 32768 threads
  int c0 = 0;
  for (int i = gid; i < 200000; i += 32768) c0 += ((xu[i] & 0x7F80) == 0x7F80) ? 1 : 0;
  if (c0) atomicAdd(&flags[0], c0);
  if (gid < 2048 && ei[1 + gid * 586] != 0) atomicAdd(&flags[1], 1);
  if (gid < 2000 && bat[1 + gid * 24] != 0) atomicAdd(&flags[2], 1);
}

__device__ __forceinline__ void load_edge(const int* __restrict__ ei, bool is64, int e,
                                          int& s, int& d) {
  if (is64) {
    s = (int)((const i64*)ei)[e];
    d = (int)((const i64*)ei)[(size_t)N_EDGES + e];
  } else {
    s = ei[e];
    d = ei[N_EDGES + e];
  }
  s = min(max(s, 0), N_NODES - 1);
  d = min(max(d, 0), N_NODES - 1);
}

// ---------------- x → bf16 Hb (once) ----------------
__global__ void convert_x(const void* __restrict__ x, const int* __restrict__ flags,
                          u16* __restrict__ Hb) {
  int i = blockIdx.x * 256 + threadIdx.x;     // 8-elem chunk id
  const int total = N_NODES * DIM / 8;        // 800000
  if (i >= total) return;
  union { u16 h[8]; uint4 q; } pk;
  if (flags[0] > 0) {
    const float4* xf = (const float4*)x;
    float4 a = xf[(size_t)i * 2], b = xf[(size_t)i * 2 + 1];
    pk.h[0] = f2bf(a.x); pk.h[1] = f2bf(a.y); pk.h[2] = f2bf(a.z); pk.h[3] = f2bf(a.w);
    pk.h[4] = f2bf(b.x); pk.h[5] = f2bf(b.y); pk.h[6] = f2bf(b.z); pk.h[7] = f2bf(b.w);
  } else {
    pk.q = ((const uint4*)x)[i];
  }
  ((uint4*)Hb)[i] = pk.q;
}

// ---------------- weight prep: WT[(l*4+m)][j*128+k] = bf16(W[k][j]) ----------
__global__ void prep_wt(const void* __restrict__ Wq, const void* __restrict__ Wk,
                        const void* __restrict__ Wv, const void* __restrict__ Ws,
                        u16* __restrict__ WT, const int* __restrict__ flags) {
  int b = blockIdx.x;            // 0..11 = l*4+m
  int l = b >> 2, m = b & 3;
  bool f32 = flags[0] > 0;
  const void* W = (m == 0 ? Wq : m == 1 ? Wk : m == 2 ? Wv : Ws);
  size_t base = (size_t)l * DIM * DIM;
  u16* out = WT + (size_t)b * DIM * DIM;
  for (int idx = threadIdx.x; idx < DIM * DIM; idx += 256) {
    int j = idx >> 7, k = idx & 127;
    float v;
    if (f32) v = ((const float*)W)[base + (size_t)k * DIM + j];
    else     v = bf2f(((const u16*)W)[base + (size_t)k * DIM + j]);
    out[idx] = f2bf(v);
  }
}

__global__ void canon_bias(const void* __restrict__ bq, const void* __restrict__ bk,
                           const void* __restrict__ bv, const void* __restrict__ bs,
                           float* __restrict__ biasc, const int* __restrict__ flags) {
  bool f32 = flags[0] > 0;
  for (int idx = threadIdx.x; idx < 12 * DIM; idx += 256) {
    int b = idx >> 7, d = idx & 127;
    int l = b >> 2, m = b & 3;
    const void* p = (m == 0 ? bq : m == 1 ? bk : m == 2 ? bv : bs);
    float v;
    if (f32) v = ((const float*)p)[l * DIM + d];
    else     v = bf2f(((const u16*)p)[l * DIM + d]);
    biasc[idx] = v;
  }
}

// ---------------- fused q/k/v/skip GEMM: bf16 H, one matrix per block ----------
__global__ __launch_bounds__(256) void gemm_qkvs(
    const u16* __restrict__ Hb, const u16* __restrict__ WT,
    const float* __restrict__ biasc,
    u16* __restrict__ Q, u16* __restrict__ K, u16* __restrict__ V, u16* __restrict__ S) {
  __shared__ u16 As[64][136];    // 17.4 KB
  __shared__ u16 Bs[128][136];   // 34.8 KB
  int tid = threadIdx.x;
  int r0 = blockIdx.x * 64;
  int mat = blockIdx.y;
  const u16* Wt = WT + (size_t)mat * DIM * DIM;

  for (int it = 0; it < 4; ++it) {
    int i16 = it * 256 + tid;
    int row = i16 >> 4, seg = i16 & 15;
    uint4 val = make_uint4(0, 0, 0, 0);
    if (r0 + row < N_NODES) val = ((const uint4*)Hb)[(size_t)(r0 + row) * 16 + seg];
    *((uint4*)&As[row][seg * 8]) = val;
  }
  for (int it = 0; it < 8; ++it) {
    int i16 = it * 256 + tid;
    int j = i16 >> 4, seg = i16 & 15;
    uint4 val = ((const uint4*)Wt)[j * 16 + seg];
    *((uint4*)&Bs[j][seg * 8]) = val;
  }
  __syncthreads();

  int lane = tid & 63;
  int w = tid >> 6;
  int wm = w & 1, wn = w >> 1;
  int lrow = lane & 15;
  int kq = (lane >> 4) * 8;
  f32x4 acc[2][4] = {};
#pragma unroll
  for (int kt = 0; kt < 4; ++kt) {
    int k0 = kt * 32 + kq;
    bf16x8 a0 = *((const bf16x8*)&As[wm * 32 + lrow][k0]);
    bf16x8 a1 = *((const bf16x8*)&As[wm * 32 + 16 + lrow][k0]);
#pragma unroll
    for (int ni = 0; ni < 4; ++ni) {
      bf16x8 b = *((const bf16x8*)&Bs[wn * 64 + ni * 16 + lrow][k0]);
      acc[0][ni] = __builtin_amdgcn_mfma_f32_16x16x32_bf16(a0, b, acc[0][ni], 0, 0, 0);
      acc[1][ni] = __builtin_amdgcn_mfma_f32_16x16x32_bf16(a1, b, acc[1][ni], 0, 0, 0);
    }
  }

  const float* bias = biasc + mat * DIM;
  u16* Out = (mat == 0 ? Q : mat == 1 ? K : mat == 2 ? V : S);
#pragma unroll
  for (int mi = 0; mi < 2; ++mi)
#pragma unroll
    for (int ni = 0; ni < 4; ++ni) {
      int colg = wn * 64 + ni * 16 + lrow;
      float bvf = bias[colg];
#pragma unroll
      for (int r = 0; r < 4; ++r) {
        int rowg = r0 + wm * 32 + mi * 16 + (lane >> 4) * 4 + r;
        if (rowg < N_NODES) {
          float o = acc[mi][ni][r] + bvf;
          if (!(o - o == 0.0f)) o = 7000.0f;
          Out[(size_t)rowg * DIM + colg] = f2bf(o);
        }
      }
    }
}

// ---------------- CSR build ----------------
__global__ void count_deg(const int* __restrict__ ei, const int* __restrict__ flags,
                          int* __restrict__ deg) {
  int e = blockIdx.x * 256 + threadIdx.x;
  if (e < N_EDGES) {
    int s, d;
    load_edge(ei, flags[1] == 0, e, s, d);
    atomicAdd(&deg[d], 1);
  }
}

__global__ void scan_blk(const int* __restrict__ deg, int* __restrict__ row_ptr,
                         int* __restrict__ blksum) {
  __shared__ int buf[1024];
  int tid = threadIdx.x;
  int idx = blockIdx.x * 1024 + tid;
  int v = (idx < N_NODES) ? deg[idx] : 0;
  buf[tid] = v;
  __syncthreads();
  for (int off = 1; off < 1024; off <<= 1) {
    int t = (tid >= off) ? buf[tid - off] : 0;
    __syncthreads();
    buf[tid] += t;
    __syncthreads();
  }
  if (idx < N_NODES) row_ptr[idx + 1] = buf[tid];
  if (tid == 1023) blksum[blockIdx.x] = buf[1023];
}

__global__ void scan_sums(int* __restrict__ blksum, int nblk) {
  if (threadIdx.x == 0) {
    int run = 0;
    for (int b = 0; b < nblk; ++b) { int t = blksum[b]; blksum[b] = run; run += t; }
  }
}

__global__ void scan_add(int* __restrict__ row_ptr, const int* __restrict__ blksum) {
  int idx = blockIdx.x * 1024 + threadIdx.x;
  if (idx < N_NODES) row_ptr[idx + 1] += blksum[blockIdx.x];
  if (idx == 0) row_ptr[0] = 0;
}

__global__ void fill_csr(const int* __restrict__ ei, const int* __restrict__ flags,
                         const int* __restrict__ row_ptr, int* __restrict__ deg,
                         int* __restrict__ csr_src) {
  int e = blockIdx.x * 256 + threadIdx.x;
  if (e < N_EDGES) {
    int s, d;
    load_edge(ei, flags[1] == 0, e, s, d);
    int c = atomicSub(&deg[d], 1);
    int pos = row_ptr[d] + c - 1;
    if (pos >= 0 && pos < N_EDGES) csr_src[pos] = s;
  }
}

// ---------------- attention: 1 wave/node, 4x16, 2-stage register pipeline ----------
// group g (of 4) handles edges start+g, start+g+4, ...; lane sl covers dims sl*8..+7.
// Next iteration's csr index + K/V rows are loaded before processing current regs.
__global__ __launch_bounds__(256) void attn_agg(
    const u16* __restrict__ Q, const u16* __restrict__ Kb,
    const u16* __restrict__ V, const u16* __restrict__ S,
    const int* __restrict__ row_ptr, const int* __restrict__ csr_src,
    void* __restrict__ Hout, int apply_relu, int out_f32) {
  int wid = threadIdx.x >> 6;
  int lane = threadIdx.x & 63;
  int n = blockIdx.x * 4 + wid;
  if (n >= N_NODES) return;
  int g = lane >> 4;            // 0..3
  int sl = lane & 15;           // 0..15
  int d0 = sl * 8;
  uint4 qv = *((const uint4*)&Q[(size_t)n * DIM + d0]);
  float q[8]; unpack8(qv, q);
  int start = row_ptr[n], end = row_ptr[n + 1];
  start = min(max(start, 0), N_EDGES);
  end = min(max(end, start), N_EDGES);
  const float scale = 0.0883883476483184f;  // 1/sqrt(128)
  float m = -INFINITY, lsum = 0.f;
  float acc[8] = {};

  int e = start + g;
  uint4 kv = make_uint4(0, 0, 0, 0), vv = make_uint4(0, 0, 0, 0);
  if (e < end) {
    int srcn = min(max(csr_src[e], 0), N_NODES - 1);
    kv = *((const uint4*)&Kb[(size_t)srcn * DIM + d0]);
    vv = *((const uint4*)&V[(size_t)srcn * DIM + d0]);
  }
  while (e < end) {
    int e2 = e + 4;
    uint4 kv2 = make_uint4(0, 0, 0, 0), vv2 = make_uint4(0, 0, 0, 0);
    if (e2 < end) {
      int srcn2 = min(max(csr_src[e2], 0), N_NODES - 1);
      kv2 = *((const uint4*)&Kb[(size_t)srcn2 * DIM + d0]);
      vv2 = *((const uint4*)&V[(size_t)srcn2 * DIM + d0]);
    }
    float kf[8], vf[8];
    unpack8(kv, kf); unpack8(vv, vf);
    float p = q[0] * kf[0] + q[1] * kf[1] + q[2] * kf[2] + q[3] * kf[3]
            + q[4] * kf[4] + q[5] * kf[5] + q[6] * kf[6] + q[7] * kf[7];
    p += __shfl_xor(p, 1, 64);
    p += __shfl_xor(p, 2, 64);
    p += __shfl_xor(p, 4, 64);
    p += __shfl_xor(p, 8, 64);
    float s = p * scale;
    float mn = fmaxf(m, s);
    float wold = __expf(m - mn);
    float wnew = __expf(s - mn);
    lsum = lsum * wold + wnew;
#pragma unroll
    for (int j = 0; j < 8; ++j) acc[j] = acc[j] * wold + wnew * vf[j];
    m = mn;
    kv = kv2; vv = vv2; e = e2;
  }
  // merge the 4 per-group states (same dims live in lanes sl, sl+16, sl+32, sl+48)
#pragma unroll
  for (int off = 16; off <= 32; off <<= 1) {
    float mo = __shfl_xor(m, off, 64);
    float lo = __shfl_xor(lsum, off, 64);
    float ao[8];
#pragma unroll
    for (int j = 0; j < 8; ++j) ao[j] = __shfl_xor(acc[j], off, 64);
    float mn = fmaxf(m, mo);
    float wa = (m  > -INFINITY) ? __expf(m  - mn) : 0.f;
    float wb = (mo > -INFINITY) ? __expf(mo - mn) : 0.f;
    lsum = lsum * wa + lo * wb;
#pragma unroll
    for (int j = 0; j < 8; ++j) acc[j] = acc[j] * wa + ao[j] * wb;
    m = mn;
  }
  float inv = (lsum > 0.f) ? (1.0f / lsum) : 0.f;
  uint4 sv = *((const uint4*)&S[(size_t)n * DIM + d0]);
  float sf[8]; unpack8(sv, sf);
  float o[8];
#pragma unroll
  for (int j = 0; j < 8; ++j) {
    float v = acc[j] * inv + sf[j];
    if (apply_relu) v = (v >= 0.f) ? v : 0.01f * v;
    if (!(v - v == 0.0f)) v = 9000.0f;
    o[j] = v;
  }
  if (g == 0) {
    if (out_f32) {
      float* H = (float*)Hout;
      *((float4*)&H[(size_t)n * DIM + d0]) = make_float4(o[0], o[1], o[2], o[3]);
      *((float4*)&H[(size_t)n * DIM + d0 + 4]) = make_float4(o[4], o[5], o[6], o[7]);
    } else {
      union { u16 h[8]; uint4 q; } pk;
#pragma unroll
      for (int j = 0; j < 8; ++j) pk.h[j] = f2bf(o[j]);
      *((uint4*)&((u16*)Hout)[(size_t)n * DIM + d0]) = pk.q;
    }
  }
}

// ---------------- parallel mean pool ----------------
__device__ __forceinline__ int bat_at(const int* bat, int i, bool is64) {
  return is64 ? (int)((const i64*)bat)[i] : bat[i];
}

__global__ __launch_bounds__(128) void pool_partial(
    const float* __restrict__ node_emb, const int* __restrict__ bat,
    const int* __restrict__ flags, float* __restrict__ gsum, float* __restrict__ gcnt) {
  int t = threadIdx.x;
  int r0 = blockIdx.x * POOL_ROWS;
  int rend = min(r0 + POOL_ROWS, N_NODES);
  if (r0 >= rend) return;
  bool is64 = (flags[2] == 0);
  int cur = min(max(bat_at(bat, r0, is64), 0), NGRAPH - 1);
  float acc = 0.f;
  int cnt = 0;
  for (int i = r0; i < rend; ++i) {
    int b = min(max(bat_at(bat, i, is64), 0), NGRAPH - 1);
    if (b != cur) {
      atomicAdd(&gsum[cur * DIM + t], acc);
      if (t == 0) atomicAdd(&gcnt[cur], (float)cnt);
      acc = 0.f; cnt = 0; cur = b;
    }
    acc += node_emb[(size_t)i * DIM + t];
    ++cnt;
  }
  atomicAdd(&gsum[cur * DIM + t], acc);
  if (t == 0) atomicAdd(&gcnt[cur], (float)cnt);
}

__global__ void pool_final(const float* __restrict__ gsum, const float* __restrict__ gcnt,
                           float* __restrict__ graph_emb) {
  int i = blockIdx.x * 256 + threadIdx.x;
  if (i < NGRAPH * DIM) {
    int b = i >> 7;
    float g = gsum[i] / fmaxf(gcnt[b], 1.0f);
    if (!(g - g == 0.0f)) g = 5555.0f;
    graph_emb[i] = g;
  }
}

extern "C" void kernel_launch(void* const* d_in, const int* in_sizes, int n_in,
                              void* d_out, int out_size, void* d_ws, size_t ws_size,
                              hipStream_t stream) {
  static const int EXP_SIZES[11] = {6400000, 1200000, 50000,
                                    49152, 384, 49152, 384, 49152, 384, 49152, 384};
  {
    float code = 0.0f;
    if (n_in != 11) code = 40000.0f;
    else if (out_size != 6416384) code = 42000.0f;
    else {
      for (int i = 0; i < 11; ++i)
        if (in_sizes[i] != EXP_SIZES[i]) { code = 44000.0f + 400.0f * i; break; }
    }
    if (code != 0.0f) {
      sentinel_fill<<<(out_size + 255) / 256, 256, 0, stream>>>((float*)d_out, out_size, code);
      return;
    }
  }

  const u16* x   = (const u16*)d_in[0];
  const int* ei  = (const int*)d_in[1];
  const int* bat = (const int*)d_in[2];

  const size_t NEEDED = 54465936;
  if (ws_size < NEEDED) {
    float code = 1000.0f + (float)(ws_size >> 20);
    sentinel_fill<<<(out_size + 255) / 256, 256, 0, stream>>>((float*)d_out, out_size, code);
    return;
  }

  char* w = (char*)d_ws;
  int*   flags   = (int*)w;   w += 256;
  int*   blksum  = (int*)w;   w += 256;
  float* gsum    = (float*)w; w += (size_t)NGRAPH * DIM * 4;
  float* gcnt    = (float*)w; w += (size_t)NGRAPH * 4;
  int*   deg     = (int*)w;   w += (size_t)N_NODES * 4;
  int*   row_ptr = (int*)w;   w += (size_t)(N_NODES + 4) * 4;
  int*   csr_src = (int*)w;   w += (size_t)N_EDGES * 4;
  u16*   WT      = (u16*)w;   w += (size_t)12 * DIM * DIM * 2;
  float* biasc   = (float*)w; w += (size_t)12 * DIM * 4;
  const size_t ND2 = (size_t)N_NODES * DIM * 2;
  u16* Qb = (u16*)w; w += ND2;
  u16* Kb = (u16*)w; w += ND2;
  u16* Vb = (u16*)w; w += ND2;
  u16* Sb = (u16*)w; w += ND2;

  hipMemsetAsync(flags, 0, 512 + 65536 + 512 + (size_t)N_NODES * 4, stream);

  detect_dtypes<<<128, 256, 0, stream>>>(x, ei, bat, flags);
  prep_wt<<<12, 256, 0, stream>>>(d_in[3], d_in[5], d_in[7], d_in[9], WT, flags);
  canon_bias<<<1, 256, 0, stream>>>(d_in[4], d_in[6], d_in[8], d_in[10], biasc, flags);

  u16* Hb = (u16*)d_out;   // bf16 h aliases d_out node region (fp32) — safe, see R11
  convert_x<<<(N_NODES * DIM / 8 + 255) / 256, 256, 0, stream>>>(x, flags, Hb);

  int eblocks = (N_EDGES + 255) / 256;
  int nblk = (N_NODES + 1023) / 1024;   // 49
  count_deg<<<eblocks, 256, 0, stream>>>(ei, flags, deg);
  scan_blk<<<nblk, 1024, 0, stream>>>(deg, row_ptr, blksum);
  scan_sums<<<1, 64, 0, stream>>>(blksum, nblk);
  scan_add<<<nblk, 1024, 0, stream>>>(row_ptr, blksum);
  fill_csr<<<eblocks, 256, 0, stream>>>(ei, flags, row_ptr, deg, csr_src);

  float* node_out = (float*)d_out;
  for (int l = 0; l < 3; ++l) {
    gemm_qkvs<<<dim3((N_NODES + 63) / 64, 4), 256, 0, stream>>>(
        Hb, WT + (size_t)l * 4 * DIM * DIM, biasc + (size_t)l * 4 * DIM,
        Qb, Kb, Vb, Sb);
    if (l < 2)
      attn_agg<<<(N_NODES + 3) / 4, 256, 0, stream>>>(Qb, Kb, Vb, Sb, row_ptr, csr_src,
                                                      (void*)Hb, 1, 0);
    else
      attn_agg<<<(N_NODES + 3) / 4, 256, 0, stream>>>(Qb, Kb, Vb, Sb, row_ptr, csr_src,
                                                      (void*)node_out, 0, 1);
  }
  int pblocks = (N_NODES + POOL_ROWS - 1) / POOL_ROWS;   // 500
  pool_partial<<<pblocks, 128, 0, stream>>>(node_out, bat, flags, gsum, gcnt);
  pool_final<<<(NGRAPH * DIM + 255) / 256, 256, 0, stream>>>(gsum, gcnt,
                                                             node_out + (size_t)N_NODES * DIM);
}